// Round 7
// baseline (4093.463 us; speedup 1.0000x reference)
//
#include <hip/hip_runtime.h>
#include <math.h>

#define NNODES 500000
#define NEDGES 16000000

// ---------------------------------------------------------------------------
// 2-layer GCN, fused. edge_index dtype (int32 vs int64) is DETECTED at
// runtime: indices < 5e5 < 2^31, so an int64 buffer has all-zero high words;
// an int32 buffer has random node IDs at odd word positions. k_detect samples
// 1024 high-words and writes a flag; consumers branch wave-uniformly on it.
//
// Algebraic transform: layer-1 aggregates the RAW 2-wide features:
//   A_norm @ (x @ W1) == (A_norm @ x) @ W1   ->  2 atomics/edge, no h1 array.
// Self-loops analytic: deg += 1; out += h[i] * dinv[i]^2.
// Index clamp: garbage indices -> wrong answer + counters, never a core dump.
//
// Workspace (floats):
//   [0,   N)  deg   -> overwritten in-place with dinv = rsqrt(deg+1)
//   [N,  3N)  aggX  (N x 2)  zeroed each call (layer-1 agg of x)
//   [3N, 5N)  agg2  (N x 2)  zeroed each call (layer-2 agg of h2)
//   [5N, 7N)  h2    (N x 2)  fully written before read
//   [7N]      flag  (int)    1 = edge_index is int64, 0 = int32
// ---------------------------------------------------------------------------

__device__ __forceinline__ void atomAddF(float* p, float v) {
    unsafeAtomicAdd(p, v);  // global_atomic_add_f32 on gfx950
}

__device__ __forceinline__ int clampIdx(int i) {
    return ((unsigned)i < (unsigned)NNODES) ? i : 0;
}

// Load 4 consecutive indices starting at element 4*i, from either layout.
// For I64, p is the int32 view of an int64 array (base must be 8B-aligned).
template <bool I64>
__device__ __forceinline__ int4 loadIdx4(const int* __restrict__ p, int i) {
    if (!I64) {
        return ((const int4*)p)[i];
    } else {
        const longlong2* q = (const longlong2*)p;
        longlong2 a = q[2 * i];
        longlong2 b = q[2 * i + 1];
        return make_int4((int)a.x, (int)a.y, (int)b.x, (int)b.y);
    }
}

// Single-block dtype probe. Samples ei32[2k+1] for k spread over [0, E):
// touches at most int32 index 2E-1, in-bounds under either layout.
__global__ __launch_bounds__(256) void k_detect(
        const int* __restrict__ ei, int* __restrict__ flag) {
    __shared__ int any_nz;
    if (threadIdx.x == 0) any_nz = 0;
    __syncthreads();
    int nz = 0;
    const int SAMPLES = 1024;
    const int step = NEDGES / SAMPLES;
    for (int t = threadIdx.x; t < SAMPLES; t += blockDim.x) {
        int k = t * step;
        nz |= (ei[2 * k + 1] != 0);
    }
    if (nz) atomicOr(&any_nz, 1);
    __syncthreads();
    if (threadIdx.x == 0) flag[0] = any_nz ? 0 : 1;   // all-zero hi words => int64
}

// Zero the accumulator region (deg + aggX + agg2 = 5N floats, 5N%4==0).
__global__ __launch_bounds__(256) void k_zero(float4* __restrict__ p, int n4) {
    int stride = gridDim.x * blockDim.x;
    for (int i = blockIdx.x * blockDim.x + threadIdx.x; i < n4; i += stride)
        p[i] = make_float4(0.f, 0.f, 0.f, 0.f);
}

// ---- degree pass -----------------------------------------------------------
template <bool I64>
__device__ __forceinline__ void degree_body(
        const int* __restrict__ dst, const float* __restrict__ ew,
        float* __restrict__ deg, int Q) {
    int stride = gridDim.x * blockDim.x;
    for (int i = blockIdx.x * blockDim.x + threadIdx.x; i < Q; i += stride) {
        int4   d = loadIdx4<I64>(dst, i);
        float4 w = ((const float4*)ew)[i];
        atomAddF(&deg[clampIdx(d.x)], w.x);
        atomAddF(&deg[clampIdx(d.y)], w.y);
        atomAddF(&deg[clampIdx(d.z)], w.z);
        atomAddF(&deg[clampIdx(d.w)], w.w);
    }
}

__global__ __launch_bounds__(256) void k_degree(
        const int* __restrict__ ei, const int* __restrict__ flag,
        const float* __restrict__ ew, float* __restrict__ deg, int Q) {
    if (flag[0]) degree_body<true >(ei + 2 * (size_t)NEDGES, ew, deg, Q);
    else         degree_body<false>(ei + (size_t)NEDGES,     ew, deg, Q);
}

// Pass 1: dinv = rsqrt(deg + 1)  (+1 = self-loop weight).
__global__ __launch_bounds__(256) void k_dinv(float* __restrict__ deg, int N) {
    int i = blockIdx.x * blockDim.x + threadIdx.x;
    if (i >= N) return;
    deg[i] = rsqrtf(deg[i] + 1.0f);
}

// ---- edge pass (both layers) ----------------------------------------------
template <bool I64>
__device__ __forceinline__ void edge_body(
        const int* __restrict__ src, const int* __restrict__ dst,
        const float* __restrict__ ew, const float* __restrict__ dinv,
        const float* __restrict__ feat, float* __restrict__ agg, int Q) {
    int stride = gridDim.x * blockDim.x;
    for (int i = blockIdx.x * blockDim.x + threadIdx.x; i < Q; i += stride) {
        int4   s = loadIdx4<I64>(src, i);
        int4   d = loadIdx4<I64>(dst, i);
        float4 w = ((const float4*)ew)[i];
        s.x = clampIdx(s.x); s.y = clampIdx(s.y);
        s.z = clampIdx(s.z); s.w = clampIdx(s.w);
        d.x = clampIdx(d.x); d.y = clampIdx(d.y);
        d.z = clampIdx(d.z); d.w = clampIdx(d.w);

        float n0 = dinv[s.x] * w.x * dinv[d.x];
        float n1 = dinv[s.y] * w.y * dinv[d.y];
        float n2 = dinv[s.z] * w.z * dinv[d.z];
        float n3 = dinv[s.w] * w.w * dinv[d.w];

        float2 f0 = ((const float2*)feat)[s.x];
        float2 f1 = ((const float2*)feat)[s.y];
        float2 f2 = ((const float2*)feat)[s.z];
        float2 f3 = ((const float2*)feat)[s.w];

        float* o0 = agg + 2 * (size_t)d.x;
        float* o1 = agg + 2 * (size_t)d.y;
        float* o2 = agg + 2 * (size_t)d.z;
        float* o3 = agg + 2 * (size_t)d.w;
        atomAddF(o0,     f0.x * n0);
        atomAddF(o0 + 1, f0.y * n0);
        atomAddF(o1,     f1.x * n1);
        atomAddF(o1 + 1, f1.y * n1);
        atomAddF(o2,     f2.x * n2);
        atomAddF(o2 + 1, f2.y * n2);
        atomAddF(o3,     f3.x * n3);
        atomAddF(o3 + 1, f3.y * n3);
    }
}

__global__ __launch_bounds__(256) void k_edge(
        const int* __restrict__ ei, const int* __restrict__ flag,
        const float* __restrict__ ew, const float* __restrict__ dinv,
        const float* __restrict__ feat, float* __restrict__ agg, int Q) {
    if (flag[0]) edge_body<true >(ei, ei + 2 * (size_t)NEDGES, ew, dinv, feat, agg, Q);
    else         edge_body<false>(ei, ei + (size_t)NEDGES,     ew, dinv, feat, agg, Q);
}

// Pass 3: layer-1 finish ((aggX + x*s^2) @ W1 + b1, relu) then @ W2 -> h2.
__global__ __launch_bounds__(256) void k_mid(
        const float* __restrict__ aggX, const float* __restrict__ x,
        const float* __restrict__ dinv, const float* __restrict__ W1,
        const float* __restrict__ b1, const float* __restrict__ W2,
        float* __restrict__ h2, int N) {
    int i = blockIdx.x * blockDim.x + threadIdx.x;
    if (i >= N) return;
    float s  = dinv[i];
    float s2 = s * s;
    float2 xa = ((const float2*)x)[i];
    float2 ag = ((const float2*)aggX)[i];
    float vx = ag.x + xa.x * s2;
    float vy = ag.y + xa.y * s2;
    float o0 = 0.f, o1 = 0.f;
#pragma unroll
    for (int j = 0; j < 8; ++j) {
        float t = fmaf(vx, W1[j], fmaf(vy, W1[8 + j], b1[j]));
        t = fmaxf(t, 0.0f);
        o0 = fmaf(t, W2[2 * j],     o0);
        o1 = fmaf(t, W2[2 * j + 1], o1);
    }
    ((float2*)h2)[i] = make_float2(o0, o1);
}

// Pass 5: layer-2 finish (self-loop + bias) and 2-class softmax.
__global__ __launch_bounds__(256) void k_fin(
        const float* __restrict__ agg2, const float* __restrict__ h2,
        const float* __restrict__ dinv, const float* __restrict__ b2,
        float* __restrict__ out, int N) {
    int i = blockIdx.x * blockDim.x + threadIdx.x;
    if (i >= N) return;
    float s  = dinv[i];
    float s2 = s * s;
    float2 a = ((const float2*)agg2)[i];
    float2 h = ((const float2*)h2)[i];
    float o0 = a.x + h.x * s2 + b2[0];
    float o1 = a.y + h.y * s2 + b2[1];
    float m  = fmaxf(o0, o1);
    float e0 = expf(o0 - m), e1 = expf(o1 - m);
    float inv = 1.0f / (e0 + e1);
    ((float2*)out)[i] = make_float2(e0 * inv, e1 * inv);
}

extern "C" void kernel_launch(void* const* d_in, const int* in_sizes, int n_in,
                              void* d_out, int out_size, void* d_ws, size_t ws_size,
                              hipStream_t stream) {
    const float* x  = (const float*)d_in[0];
    const int*   ei = (const int*)d_in[1];   // int32 view; layout per flag
    const float* ew = (const float*)d_in[2];
    const float* W1 = (const float*)d_in[3];
    const float* b1 = (const float*)d_in[4];
    const float* W2 = (const float*)d_in[5];
    const float* b2 = (const float*)d_in[6];
    float* out = (float*)d_out;
    float* ws  = (float*)d_ws;

    const int N = NNODES, E = NEDGES, Q = E / 4;

    float* deg  = ws;                   // N   (becomes dinv)
    float* aggX = ws + (size_t)N;       // 2N
    float* agg2 = ws + (size_t)3 * N;   // 2N
    float* h2   = ws + (size_t)5 * N;   // 2N
    int*   flag = (int*)(ws + (size_t)7 * N);

    const int NT = 256;
    const int EB = 2048;                 // grid-stride over edge quads
    const int NB = (N + NT - 1) / NT;
    const int ZB = ((5 * N / 4) + NT - 1) / NT;

    k_detect<<<1,  NT, 0, stream>>>(ei, flag);
    k_zero  <<<ZB, NT, 0, stream>>>((float4*)ws, 5 * N / 4);
    k_degree<<<EB, NT, 0, stream>>>(ei, flag, ew, deg, Q);
    k_dinv  <<<NB, NT, 0, stream>>>(deg, N);
    k_edge  <<<EB, NT, 0, stream>>>(ei, flag, ew, deg, x, aggX, Q);
    k_mid   <<<NB, NT, 0, stream>>>(aggX, x, deg, W1, b1, W2, h2, N);
    k_edge  <<<EB, NT, 0, stream>>>(ei, flag, ew, deg, h2, agg2, Q);
    k_fin   <<<NB, NT, 0, stream>>>(agg2, h2, deg, b2, out, N);
}

// Round 9
// 921.030 us; speedup vs baseline: 4.4444x; 4.4444x over previous
//
#include <hip/hip_runtime.h>
#include <math.h>

#define NNODES 500000
#define NEDGES 16000000
#define NBINS 512
#define BINSHIFT 10
#define BINMASK 1023
#define CB 512           // blocks for count/scatter passes
#define NT 256

// ---------------------------------------------------------------------------
// Round 9 (= round-8 design + LDS-atomic hardening): global-atomic-free GCN
// via dst-binning.
// Round-7 counters: k_edge 1576us @ 14% HBM, VALUBusy 0.4%, WRITE_SIZE ~1GB
// per pass = 32M f32 atomics x 32B sector write-through (XCD L2s not
// coherent -> device-scope atomics bypass L2). Fix: bin edges by dst>>10,
// accumulate in LDS (unsafeAtomicAdd -> native ds_add_f32), write dense
// slices. No global atomics anywhere in the fast path.
//
// FAST ws layout (u32 offsets):
//   0        flag (int64/int32 detect)
//   64       binstart[513]
//   1024     tot[512]
//   2048     counts[NBINS][CB]    (262144)
//   264192   offs[NBINS][CB]      (262144)
//   526336   degrep[2][N]         (f32)
//   1526336  dinv[N]
//   2026336  agg1rep[2][N][2]
//   4026336  agg2rep[2][N][2]
//   6026336  h2[N][2]
//   7026336  records[E] uint2     (key=(dstloc<<19)|src, w)
// total = 7026336 + 2E u32 = 156.1 MB. Fallback (round-7 path) if ws smaller.
// ---------------------------------------------------------------------------

#define OFF_FLAG   0
#define OFF_BASE   64
#define OFF_TOT    1024
#define OFF_COUNTS 2048
#define OFF_OFFS   264192
#define OFF_DEGREP 526336
#define OFF_DINV   1526336
#define OFF_AGG1   2026336
#define OFF_AGG2   4026336
#define OFF_H2     6026336
#define OFF_REC    7026336
#define WS_NEED_FAST (((size_t)OFF_REC + 2ull * NEDGES) * 4ull)

__device__ __forceinline__ void atomAddF(float* p, float v) {
    unsafeAtomicAdd(p, v);  // native f32 add: global_atomic_add_f32 / ds_add_f32
}

__device__ __forceinline__ int clampIdx(int i) {
    return ((unsigned)i < (unsigned)NNODES) ? i : 0;
}

template <bool I64>
__device__ __forceinline__ int4 loadIdx4(const int* __restrict__ p, int i) {
    if (!I64) {
        return ((const int4*)p)[i];
    } else {
        const longlong2* q = (const longlong2*)p;
        longlong2 a = q[2 * i];
        longlong2 b = q[2 * i + 1];
        return make_int4((int)a.x, (int)a.y, (int)b.x, (int)b.y);
    }
}

// dtype probe: int64 buffer has all-zero high words (indices < 2^31).
__global__ __launch_bounds__(256) void k_detect(
        const int* __restrict__ ei, int* __restrict__ flag) {
    __shared__ int any_nz;
    if (threadIdx.x == 0) any_nz = 0;
    __syncthreads();
    int nz = 0;
    const int SAMPLES = 1024;
    const int step = NEDGES / SAMPLES;
    for (int t = threadIdx.x; t < SAMPLES; t += blockDim.x) {
        int k = t * step;
        nz |= (ei[2 * k + 1] != 0);
    }
    if (nz) atomicOr(&any_nz, 1);
    __syncthreads();
    if (threadIdx.x == 0) flag[0] = any_nz ? 0 : 1;
}

// ---- FAST PATH -------------------------------------------------------------

// B1: per-block LDS histogram of dst bins.
template <bool I64>
__device__ __forceinline__ void count_body(
        const int* __restrict__ dstb, unsigned* __restrict__ counts) {
    __shared__ unsigned hist[NBINS];
    for (int j = threadIdx.x; j < NBINS; j += NT) hist[j] = 0;
    __syncthreads();
    const int Q = NEDGES / 4;
    const int qpb = (Q + CB - 1) / CB;
    int q0 = blockIdx.x * qpb, q1 = min(q0 + qpb, Q);
    for (int i = q0 + threadIdx.x; i < q1; i += NT) {
        int4 d = loadIdx4<I64>(dstb, i);
        atomicAdd(&hist[clampIdx(d.x) >> BINSHIFT], 1u);
        atomicAdd(&hist[clampIdx(d.y) >> BINSHIFT], 1u);
        atomicAdd(&hist[clampIdx(d.z) >> BINSHIFT], 1u);
        atomicAdd(&hist[clampIdx(d.w) >> BINSHIFT], 1u);
    }
    __syncthreads();
    for (int j = threadIdx.x; j < NBINS; j += NT)
        counts[(size_t)j * CB + blockIdx.x] = hist[j];
}

__global__ __launch_bounds__(256) void kb_count(
        const int* __restrict__ ei, const int* __restrict__ flag,
        unsigned* __restrict__ counts) {
    if (flag[0]) count_body<true >(ei + 2 * (size_t)NEDGES, counts);
    else         count_body<false>(ei + (size_t)NEDGES,     counts);
}

// T1: per-bin totals.
__global__ __launch_bounds__(256) void kb_tot(
        const unsigned* __restrict__ counts, unsigned* __restrict__ tot) {
    int b = blockIdx.x, t = threadIdx.x;
    __shared__ unsigned r[NT];
    r[t] = counts[(size_t)b * CB + t] + counts[(size_t)b * CB + t + 256];
    __syncthreads();
    for (int d = NT / 2; d > 0; d >>= 1) {
        if (t < d) r[t] += r[t + d];
        __syncthreads();
    }
    if (t == 0) tot[b] = r[0];
}

// S1: exclusive scan of 512 bin totals -> binstart[0..512].
__global__ __launch_bounds__(256) void kb_scanbase(
        const unsigned* __restrict__ tot, unsigned* __restrict__ base) {
    __shared__ unsigned sc[NBINS];
    int t = threadIdx.x;
    unsigned o0 = tot[t], o1 = tot[t + 256];
    sc[t] = o0; sc[t + 256] = o1;
    __syncthreads();
    for (int d = 1; d < NBINS; d <<= 1) {
        unsigned a0 = (t >= d) ? sc[t - d] : 0u;
        unsigned a1 = (t + 256 >= d) ? sc[t + 256 - d] : 0u;
        __syncthreads();
        sc[t] += a0; sc[t + 256] += a1;
        __syncthreads();
    }
    base[t] = sc[t] - o0;
    base[t + 256] = sc[t + 256] - o1;
    if (t == 255) base[NBINS] = sc[NBINS - 1];
}

// S2: per-bin exclusive scan over blocks -> absolute record offsets.
__global__ __launch_bounds__(256) void kb_offsets(
        const unsigned* __restrict__ counts, const unsigned* __restrict__ base,
        unsigned* __restrict__ offs) {
    int b = blockIdx.x, t = threadIdx.x;
    __shared__ unsigned sc[CB];
    unsigned o0 = counts[(size_t)b * CB + t], o1 = counts[(size_t)b * CB + t + 256];
    sc[t] = o0; sc[t + 256] = o1;
    __syncthreads();
    for (int d = 1; d < CB; d <<= 1) {
        unsigned a0 = (t >= d) ? sc[t - d] : 0u;
        unsigned a1 = (t + 256 >= d) ? sc[t + 256 - d] : 0u;
        __syncthreads();
        sc[t] += a0; sc[t + 256] += a1;
        __syncthreads();
    }
    unsigned bb = base[b];
    offs[(size_t)b * CB + t]       = bb + sc[t] - o0;
    offs[(size_t)b * CB + t + 256] = bb + sc[t + 256] - o1;
}

// B3: scatter edge records into per-bin segments (LDS cursors, no g-atomics).
template <bool I64>
__device__ __forceinline__ void scatter_body(
        const int* __restrict__ srcb, const int* __restrict__ dstb,
        const float* __restrict__ ew, const unsigned* __restrict__ offs,
        uint2* __restrict__ rec) {
    __shared__ unsigned cur[NBINS];
    for (int j = threadIdx.x; j < NBINS; j += NT)
        cur[j] = offs[(size_t)j * CB + blockIdx.x];
    __syncthreads();
    const int Q = NEDGES / 4;
    const int qpb = (Q + CB - 1) / CB;
    int q0 = blockIdx.x * qpb, q1 = min(q0 + qpb, Q);
    for (int i = q0 + threadIdx.x; i < q1; i += NT) {
        int4   s = loadIdx4<I64>(srcb, i);
        int4   d = loadIdx4<I64>(dstb, i);
        float4 w = ((const float4*)ew)[i];
        int sv[4] = {clampIdx(s.x), clampIdx(s.y), clampIdx(s.z), clampIdx(s.w)};
        int dv[4] = {clampIdx(d.x), clampIdx(d.y), clampIdx(d.z), clampIdx(d.w)};
        float wv[4] = {w.x, w.y, w.z, w.w};
#pragma unroll
        for (int k = 0; k < 4; ++k) {
            int bin = dv[k] >> BINSHIFT;
            unsigned slot = atomicAdd(&cur[bin], 1u);
            unsigned key = ((unsigned)(dv[k] & BINMASK) << 19) | (unsigned)sv[k];
            rec[slot] = make_uint2(key, __float_as_uint(wv[k]));
        }
    }
}

__global__ __launch_bounds__(256) void kb_scatter(
        const int* __restrict__ ei, const int* __restrict__ flag,
        const float* __restrict__ ew, const unsigned* __restrict__ offs,
        uint2* __restrict__ rec) {
    if (flag[0]) scatter_body<true >(ei, ei + 2 * (size_t)NEDGES, ew, offs, rec);
    else         scatter_body<false>(ei, ei + (size_t)NEDGES,     ew, offs, rec);
}

// B4: per-bin degree accumulation in LDS (2 blocks/bin -> 2 replicas).
__global__ __launch_bounds__(256) void kb_degree(
        const uint2* __restrict__ rec, const unsigned* __restrict__ base,
        float* __restrict__ degrep) {
    int bin = blockIdx.x >> 1, half = blockIdx.x & 1, t = threadIdx.x;
    __shared__ float sdeg[1024];
    for (int j = t; j < 1024; j += NT) sdeg[j] = 0.f;
    __syncthreads();
    int s = base[bin], e = base[bin + 1];
    int len = e - s, h = len >> 1;
    int b0 = s + (half ? h : 0);
    int b1 = half ? e : s + h;
    for (int i = b0 + t; i < b1; i += NT) {
        uint2 r = rec[i];
        atomAddF(&sdeg[r.x >> 19], __uint_as_float(r.y));
    }
    __syncthreads();
    int nodebase = bin << BINSHIFT;
    for (int j = t; j < 1024; j += NT) {
        int node = nodebase + j;
        if (node < NNODES) degrep[(size_t)half * NNODES + node] = sdeg[j];
    }
}

// dinv = rsqrt(deg0 + deg1 + 1).
__global__ __launch_bounds__(256) void kb_dinv(
        const float* __restrict__ degrep, float* __restrict__ dinv, int N) {
    int i = blockIdx.x * blockDim.x + threadIdx.x;
    if (i >= N) return;
    dinv[i] = rsqrtf(degrep[i] + degrep[(size_t)N + i] + 1.0f);
}

// B5/B7: per-bin feature aggregation in LDS. out[dst] += feat[src]*norm.
__global__ __launch_bounds__(256) void kb_agg(
        const uint2* __restrict__ rec, const unsigned* __restrict__ base,
        const float* __restrict__ dinv, const float2* __restrict__ feat,
        float2* __restrict__ outrep) {
    int bin = blockIdx.x >> 1, half = blockIdx.x & 1, t = threadIdx.x;
    __shared__ float sagg[2048];
    __shared__ float sdinv[1024];
    for (int j = t; j < 2048; j += NT) sagg[j] = 0.f;
    int nodebase = bin << BINSHIFT;
    for (int j = t; j < 1024; j += NT) {
        int node = nodebase + j;
        sdinv[j] = (node < NNODES) ? dinv[node] : 0.f;
    }
    __syncthreads();
    int s = base[bin], e = base[bin + 1];
    int len = e - s, h = len >> 1;
    int b0 = s + (half ? h : 0);
    int b1 = half ? e : s + h;
    for (int i = b0 + t; i < b1; i += NT) {
        uint2 r = rec[i];
        int dl  = r.x >> 19;
        int src = r.x & 0x7FFFF;
        float nrm = dinv[src] * __uint_as_float(r.y) * sdinv[dl];
        float2 f = feat[src];
        atomAddF(&sagg[2 * dl],     f.x * nrm);
        atomAddF(&sagg[2 * dl + 1], f.y * nrm);
    }
    __syncthreads();
    for (int j = t; j < 1024; j += NT) {
        int node = nodebase + j;
        if (node < NNODES)
            outrep[(size_t)half * NNODES + node] = make_float2(sagg[2 * j], sagg[2 * j + 1]);
    }
}

// layer-1 finish: v=(rep0+rep1 + x*s^2); h2 = relu(v@W1+b1)@W2.
__global__ __launch_bounds__(256) void kb_mid(
        const float2* __restrict__ aggrep, const float2* __restrict__ x,
        const float* __restrict__ dinv, const float* __restrict__ W1,
        const float* __restrict__ b1, const float* __restrict__ W2,
        float2* __restrict__ h2, int N) {
    int i = blockIdx.x * blockDim.x + threadIdx.x;
    if (i >= N) return;
    float s = dinv[i], s2 = s * s;
    float2 a0 = aggrep[i], a1 = aggrep[(size_t)N + i];
    float2 xa = x[i];
    float vx = a0.x + a1.x + xa.x * s2;
    float vy = a0.y + a1.y + xa.y * s2;
    float o0 = 0.f, o1 = 0.f;
#pragma unroll
    for (int j = 0; j < 8; ++j) {
        float tt = fmaf(vx, W1[j], fmaf(vy, W1[8 + j], b1[j]));
        tt = fmaxf(tt, 0.0f);
        o0 = fmaf(tt, W2[2 * j],     o0);
        o1 = fmaf(tt, W2[2 * j + 1], o1);
    }
    h2[i] = make_float2(o0, o1);
}

// layer-2 finish + softmax.
__global__ __launch_bounds__(256) void kb_fin(
        const float2* __restrict__ aggrep, const float2* __restrict__ h2,
        const float* __restrict__ dinv, const float* __restrict__ b2,
        float2* __restrict__ out, int N) {
    int i = blockIdx.x * blockDim.x + threadIdx.x;
    if (i >= N) return;
    float s = dinv[i], s2 = s * s;
    float2 a0 = aggrep[i], a1 = aggrep[(size_t)N + i];
    float2 h = h2[i];
    float o0 = a0.x + a1.x + h.x * s2 + b2[0];
    float o1 = a0.y + a1.y + h.y * s2 + b2[1];
    float m  = fmaxf(o0, o1);
    float e0 = expf(o0 - m), e1 = expf(o1 - m);
    float inv = 1.0f / (e0 + e1);
    out[i] = make_float2(e0 * inv, e1 * inv);
}

// ---- FALLBACK PATH (round-7 proven kernels) --------------------------------

__global__ __launch_bounds__(256) void k_zero(float4* __restrict__ p, int n4) {
    int stride = gridDim.x * blockDim.x;
    for (int i = blockIdx.x * blockDim.x + threadIdx.x; i < n4; i += stride)
        p[i] = make_float4(0.f, 0.f, 0.f, 0.f);
}

template <bool I64>
__device__ __forceinline__ void degree_body(
        const int* __restrict__ dst, const float* __restrict__ ew,
        float* __restrict__ deg, int Q) {
    int stride = gridDim.x * blockDim.x;
    for (int i = blockIdx.x * blockDim.x + threadIdx.x; i < Q; i += stride) {
        int4   d = loadIdx4<I64>(dst, i);
        float4 w = ((const float4*)ew)[i];
        atomAddF(&deg[clampIdx(d.x)], w.x);
        atomAddF(&deg[clampIdx(d.y)], w.y);
        atomAddF(&deg[clampIdx(d.z)], w.z);
        atomAddF(&deg[clampIdx(d.w)], w.w);
    }
}

__global__ __launch_bounds__(256) void k_degree(
        const int* __restrict__ ei, const int* __restrict__ flag,
        const float* __restrict__ ew, float* __restrict__ deg, int Q) {
    if (flag[0]) degree_body<true >(ei + 2 * (size_t)NEDGES, ew, deg, Q);
    else         degree_body<false>(ei + (size_t)NEDGES,     ew, deg, Q);
}

__global__ __launch_bounds__(256) void k_dinv(float* __restrict__ deg, int N) {
    int i = blockIdx.x * blockDim.x + threadIdx.x;
    if (i >= N) return;
    deg[i] = rsqrtf(deg[i] + 1.0f);
}

template <bool I64>
__device__ __forceinline__ void edge_body(
        const int* __restrict__ src, const int* __restrict__ dst,
        const float* __restrict__ ew, const float* __restrict__ dinv,
        const float* __restrict__ feat, float* __restrict__ agg, int Q) {
    int stride = gridDim.x * blockDim.x;
    for (int i = blockIdx.x * blockDim.x + threadIdx.x; i < Q; i += stride) {
        int4   s = loadIdx4<I64>(src, i);
        int4   d = loadIdx4<I64>(dst, i);
        float4 w = ((const float4*)ew)[i];
        s.x = clampIdx(s.x); s.y = clampIdx(s.y);
        s.z = clampIdx(s.z); s.w = clampIdx(s.w);
        d.x = clampIdx(d.x); d.y = clampIdx(d.y);
        d.z = clampIdx(d.z); d.w = clampIdx(d.w);
        float n0 = dinv[s.x] * w.x * dinv[d.x];
        float n1 = dinv[s.y] * w.y * dinv[d.y];
        float n2 = dinv[s.z] * w.z * dinv[d.z];
        float n3 = dinv[s.w] * w.w * dinv[d.w];
        float2 f0 = ((const float2*)feat)[s.x];
        float2 f1 = ((const float2*)feat)[s.y];
        float2 f2 = ((const float2*)feat)[s.z];
        float2 f3 = ((const float2*)feat)[s.w];
        float* o0 = agg + 2 * (size_t)d.x;
        float* o1 = agg + 2 * (size_t)d.y;
        float* o2 = agg + 2 * (size_t)d.z;
        float* o3 = agg + 2 * (size_t)d.w;
        atomAddF(o0,     f0.x * n0);
        atomAddF(o0 + 1, f0.y * n0);
        atomAddF(o1,     f1.x * n1);
        atomAddF(o1 + 1, f1.y * n1);
        atomAddF(o2,     f2.x * n2);
        atomAddF(o2 + 1, f2.y * n2);
        atomAddF(o3,     f3.x * n3);
        atomAddF(o3 + 1, f3.y * n3);
    }
}

__global__ __launch_bounds__(256) void k_edge(
        const int* __restrict__ ei, const int* __restrict__ flag,
        const float* __restrict__ ew, const float* __restrict__ dinv,
        const float* __restrict__ feat, float* __restrict__ agg, int Q) {
    if (flag[0]) edge_body<true >(ei, ei + 2 * (size_t)NEDGES, ew, dinv, feat, agg, Q);
    else         edge_body<false>(ei, ei + (size_t)NEDGES,     ew, dinv, feat, agg, Q);
}

__global__ __launch_bounds__(256) void k_mid(
        const float* __restrict__ aggX, const float* __restrict__ x,
        const float* __restrict__ dinv, const float* __restrict__ W1,
        const float* __restrict__ b1, const float* __restrict__ W2,
        float* __restrict__ h2, int N) {
    int i = blockIdx.x * blockDim.x + threadIdx.x;
    if (i >= N) return;
    float s = dinv[i], s2 = s * s;
    float2 xa = ((const float2*)x)[i];
    float2 ag = ((const float2*)aggX)[i];
    float vx = ag.x + xa.x * s2;
    float vy = ag.y + xa.y * s2;
    float o0 = 0.f, o1 = 0.f;
#pragma unroll
    for (int j = 0; j < 8; ++j) {
        float t = fmaf(vx, W1[j], fmaf(vy, W1[8 + j], b1[j]));
        t = fmaxf(t, 0.0f);
        o0 = fmaf(t, W2[2 * j],     o0);
        o1 = fmaf(t, W2[2 * j + 1], o1);
    }
    ((float2*)h2)[i] = make_float2(o0, o1);
}

__global__ __launch_bounds__(256) void k_fin(
        const float* __restrict__ agg2, const float* __restrict__ h2,
        const float* __restrict__ dinv, const float* __restrict__ b2,
        float* __restrict__ out, int N) {
    int i = blockIdx.x * blockDim.x + threadIdx.x;
    if (i >= N) return;
    float s = dinv[i], s2 = s * s;
    float2 a = ((const float2*)agg2)[i];
    float2 h = ((const float2*)h2)[i];
    float o0 = a.x + h.x * s2 + b2[0];
    float o1 = a.y + h.y * s2 + b2[1];
    float m  = fmaxf(o0, o1);
    float e0 = expf(o0 - m), e1 = expf(o1 - m);
    float inv = 1.0f / (e0 + e1);
    ((float2*)out)[i] = make_float2(e0 * inv, e1 * inv);
}

// ---------------------------------------------------------------------------

extern "C" void kernel_launch(void* const* d_in, const int* in_sizes, int n_in,
                              void* d_out, int out_size, void* d_ws, size_t ws_size,
                              hipStream_t stream) {
    const float* x  = (const float*)d_in[0];
    const int*   ei = (const int*)d_in[1];   // int32 view; layout per flag
    const float* ew = (const float*)d_in[2];
    const float* W1 = (const float*)d_in[3];
    const float* b1 = (const float*)d_in[4];
    const float* W2 = (const float*)d_in[5];
    const float* b2 = (const float*)d_in[6];
    float* out = (float*)d_out;
    unsigned* wsu = (unsigned*)d_ws;
    float*    wsf = (float*)d_ws;

    const int N = NNODES, E = NEDGES, Q = E / 4;
    const int NB = (N + NT - 1) / NT;
    int* flag = (int*)(wsu + OFF_FLAG);

    bool fast = ws_size >= WS_NEED_FAST;

    k_detect<<<1, NT, 0, stream>>>(ei, flag);

    if (fast) {
        unsigned* base   = wsu + OFF_BASE;
        unsigned* tot    = wsu + OFF_TOT;
        unsigned* counts = wsu + OFF_COUNTS;
        unsigned* offs   = wsu + OFF_OFFS;
        float*    degrep = wsf + OFF_DEGREP;
        float*    dinv   = wsf + OFF_DINV;
        float2*   agg1   = (float2*)(wsf + OFF_AGG1);
        float2*   agg2   = (float2*)(wsf + OFF_AGG2);
        float2*   h2     = (float2*)(wsf + OFF_H2);
        uint2*    rec    = (uint2*)(wsu + OFF_REC);

        kb_count   <<<CB,        NT, 0, stream>>>(ei, flag, counts);
        kb_tot     <<<NBINS,     NT, 0, stream>>>(counts, tot);
        kb_scanbase<<<1,         NT, 0, stream>>>(tot, base);
        kb_offsets <<<NBINS,     NT, 0, stream>>>(counts, base, offs);
        kb_scatter <<<CB,        NT, 0, stream>>>(ei, flag, ew, offs, rec);
        kb_degree  <<<2 * NBINS, NT, 0, stream>>>(rec, base, degrep);
        kb_dinv    <<<NB,        NT, 0, stream>>>(degrep, dinv, N);
        kb_agg     <<<2 * NBINS, NT, 0, stream>>>(rec, base, dinv, (const float2*)x, agg1);
        kb_mid     <<<NB,        NT, 0, stream>>>(agg1, (const float2*)x, dinv, W1, b1, W2, h2, N);
        kb_agg     <<<2 * NBINS, NT, 0, stream>>>(rec, base, dinv, (const float2*)h2, agg2);
        kb_fin     <<<NB,        NT, 0, stream>>>(agg2, h2, dinv, b2, (float2*)out, N);
    } else {
        float* deg  = wsf + 64;
        float* aggX = wsf + 64 + (size_t)N;
        float* agg2 = wsf + 64 + (size_t)3 * N;
        float* h2   = wsf + 64 + (size_t)5 * N;
        const int EB = 2048;
        const int ZB = ((5 * N / 4) + NT - 1) / NT;

        k_zero  <<<ZB, NT, 0, stream>>>((float4*)deg, 5 * N / 4);
        k_degree<<<EB, NT, 0, stream>>>(ei, flag, ew, deg, Q);
        k_dinv  <<<NB, NT, 0, stream>>>(deg, N);
        k_edge  <<<EB, NT, 0, stream>>>(ei, flag, ew, deg, x, aggX, Q);
        k_mid   <<<NB, NT, 0, stream>>>(aggX, x, deg, W1, b1, W2, h2, N);
        k_edge  <<<EB, NT, 0, stream>>>(ei, flag, ew, deg, h2, agg2, Q);
        k_fin   <<<NB, NT, 0, stream>>>(agg2, h2, deg, b2, out, N);
    }
}

// Round 12
// 879.543 us; speedup vs baseline: 4.6541x; 1.0472x over previous
//
#include <hip/hip_runtime.h>
#include <math.h>

#define NNODES 500000
#define NEDGES 16000000
#define NBINS 256        // nodes/bin = 2048
#define BINSHIFT 11
#define BINMASK 2047
#define CB 1024          // blocks for count/scatter passes
#define REP 4            // blocks per bin for degree/agg
#define NT 256

// ---------------------------------------------------------------------------
// Round 12 (= round-10 design; compile fix: __builtin_nontemporal_load needs
// native clang vector types, not HIP_vector_type classes):
// dst-binned, global-atomic-free GCN with:
//  * CB 512->1024, REP 2->4  (occupancy 20% -> ~50%)
//  * nontemporal streaming loads in count/scatter (protect L2 write-combining;
//    round-9 scatter WRITE_SIZE was 418MB vs 128MB ideal)
//  * NBINS 512->256: bigger per-(block,bin) record segments, smaller open-line
//    footprint (~2MB/XCD < 4MB L2)
//  * dinv[dst] factored out of the edge loop (applied per-node in mid/fin)
//
// ws layout (u32 words), ALIASED so total == round-9's 156,105,344 B:
//   0        flag
//   64       base[257]
//   1024     tot[256]
//   2048     counts[CB][NBINS]   (262144)   dead after scatter
//   264192   offs  [CB][NBINS]   (262144)   dead after scatter
//   526336   degrep[REP][N]      (2,000,000; lifetime degree->dinv)
//   526336   h2[N][2]            (1,000,000; lifetime mid->fin, aliases degrep)
//   2526336  dinv[N]             (500,000)
//   3026336  agg[REP][N][2]      (4,000,000; agg1 then agg2, aliased)
//   7026336  rec[E] uint2        (key=(dstloc<<19)|src, w)
// ---------------------------------------------------------------------------

#define OFF_FLAG   0
#define OFF_BASE   64
#define OFF_TOT    1024
#define OFF_COUNTS 2048
#define OFF_OFFS   264192
#define OFF_DEGREP 526336
#define OFF_H2     526336
#define OFF_DINV   2526336
#define OFF_AGG    3026336
#define OFF_REC    7026336
#define WS_NEED_FAST (((size_t)OFF_REC + 2ull * NEDGES) * 4ull)

// Native clang vector types for __builtin_nontemporal_load.
typedef int       i32x4 __attribute__((ext_vector_type(4)));
typedef float     f32x4 __attribute__((ext_vector_type(4)));
typedef long long i64x2 __attribute__((ext_vector_type(2)));

__device__ __forceinline__ void atomAddF(float* p, float v) {
    unsafeAtomicAdd(p, v);  // native f32 add: global_atomic_add_f32 / ds_add_f32
}

__device__ __forceinline__ int clampIdx(int i) {
    return ((unsigned)i < (unsigned)NNODES) ? i : 0;
}

template <bool I64>
__device__ __forceinline__ int4 loadIdx4(const int* __restrict__ p, int i) {
    if (!I64) {
        return ((const int4*)p)[i];
    } else {
        const longlong2* q = (const longlong2*)p;
        longlong2 a = q[2 * i];
        longlong2 b = q[2 * i + 1];
        return make_int4((int)a.x, (int)a.y, (int)b.x, (int)b.y);
    }
}

// Nontemporal variants for the big streaming passes (clang vector types).
template <bool I64>
__device__ __forceinline__ int4 loadIdx4NT(const int* __restrict__ p, int i) {
    if (!I64) {
        i32x4 v = __builtin_nontemporal_load(((const i32x4*)p) + i);
        return make_int4(v.x, v.y, v.z, v.w);
    } else {
        i64x2 a = __builtin_nontemporal_load(((const i64x2*)p) + 2 * i);
        i64x2 b = __builtin_nontemporal_load(((const i64x2*)p) + 2 * i + 1);
        return make_int4((int)a.x, (int)a.y, (int)b.x, (int)b.y);
    }
}

__device__ __forceinline__ float4 loadF4NT(const float* __restrict__ p, int i) {
    f32x4 v = __builtin_nontemporal_load(((const f32x4*)p) + i);
    return make_float4(v.x, v.y, v.z, v.w);
}

// dtype probe: int64 buffer has all-zero high words (indices < 2^31).
__global__ __launch_bounds__(256) void k_detect(
        const int* __restrict__ ei, int* __restrict__ flag) {
    __shared__ int any_nz;
    if (threadIdx.x == 0) any_nz = 0;
    __syncthreads();
    int nz = 0;
    const int SAMPLES = 1024;
    const int step = NEDGES / SAMPLES;
    for (int t = threadIdx.x; t < SAMPLES; t += blockDim.x) {
        int k = t * step;
        nz |= (ei[2 * k + 1] != 0);
    }
    if (nz) atomicOr(&any_nz, 1);
    __syncthreads();
    if (threadIdx.x == 0) flag[0] = any_nz ? 0 : 1;
}

// ---- FAST PATH -------------------------------------------------------------

// B1: per-block LDS histogram of dst bins (NT streaming reads).
template <bool I64>
__device__ __forceinline__ void count_body(
        const int* __restrict__ dstb, unsigned* __restrict__ counts) {
    __shared__ unsigned hist[NBINS];
    for (int j = threadIdx.x; j < NBINS; j += NT) hist[j] = 0;
    __syncthreads();
    const int Q = NEDGES / 4;
    const int qpb = (Q + CB - 1) / CB;
    int q0 = blockIdx.x * qpb, q1 = min(q0 + qpb, Q);
    for (int i = q0 + threadIdx.x; i < q1; i += NT) {
        int4 d = loadIdx4NT<I64>(dstb, i);
        atomicAdd(&hist[clampIdx(d.x) >> BINSHIFT], 1u);
        atomicAdd(&hist[clampIdx(d.y) >> BINSHIFT], 1u);
        atomicAdd(&hist[clampIdx(d.z) >> BINSHIFT], 1u);
        atomicAdd(&hist[clampIdx(d.w) >> BINSHIFT], 1u);
    }
    __syncthreads();
    for (int j = threadIdx.x; j < NBINS; j += NT)
        counts[(size_t)blockIdx.x * NBINS + j] = hist[j];
}

__global__ __launch_bounds__(256) void kb_count(
        const int* __restrict__ ei, const int* __restrict__ flag,
        unsigned* __restrict__ counts) {
    if (flag[0]) count_body<true >(ei + 2 * (size_t)NEDGES, counts);
    else         count_body<false>(ei + (size_t)NEDGES,     counts);
}

// T1: per-bin totals (sum over CB blocks; 4 elements/thread).
__global__ __launch_bounds__(256) void kb_tot(
        const unsigned* __restrict__ counts, unsigned* __restrict__ tot) {
    int j = blockIdx.x, t = threadIdx.x;
    __shared__ unsigned r[NT];
    unsigned s = 0;
#pragma unroll
    for (int k = 0; k < CB / NT; ++k)
        s += counts[(size_t)(t * (CB / NT) + k) * NBINS + j];
    r[t] = s;
    __syncthreads();
    for (int d = NT / 2; d > 0; d >>= 1) {
        if (t < d) r[t] += r[t + d];
        __syncthreads();
    }
    if (t == 0) tot[j] = r[0];
}

// S1: exclusive scan of NBINS(=256) totals -> base[0..NBINS].
__global__ __launch_bounds__(256) void kb_scanbase(
        const unsigned* __restrict__ tot, unsigned* __restrict__ base) {
    __shared__ unsigned sc[NBINS];
    int t = threadIdx.x;
    unsigned o = tot[t];
    sc[t] = o;
    __syncthreads();
    for (int d = 1; d < NBINS; d <<= 1) {
        unsigned a = (t >= d) ? sc[t - d] : 0u;
        __syncthreads();
        sc[t] += a;
        __syncthreads();
    }
    base[t] = sc[t] - o;
    if (t == NBINS - 1) base[NBINS] = sc[NBINS - 1];
}

// S2: per-bin exclusive scan over blocks -> absolute record offsets.
__global__ __launch_bounds__(256) void kb_offsets(
        const unsigned* __restrict__ counts, const unsigned* __restrict__ base,
        unsigned* __restrict__ offs) {
    int j = blockIdx.x, t = threadIdx.x;
    const int K = CB / NT;  // 4
    __shared__ unsigned part[NT];
    unsigned loc[K];
    unsigned s = 0;
#pragma unroll
    for (int k = 0; k < K; ++k) {
        loc[k] = counts[(size_t)(t * K + k) * NBINS + j];
        s += loc[k];
    }
    part[t] = s;
    __syncthreads();
    for (int d = 1; d < NT; d <<= 1) {
        unsigned a = (t >= d) ? part[t - d] : 0u;
        __syncthreads();
        part[t] += a;
        __syncthreads();
    }
    unsigned run = base[j] + part[t] - s;
#pragma unroll
    for (int k = 0; k < K; ++k) {
        offs[(size_t)(t * K + k) * NBINS + j] = run;
        run += loc[k];
    }
}

// B3: scatter edge records into per-bin segments (LDS cursors, NT reads).
template <bool I64>
__device__ __forceinline__ void scatter_body(
        const int* __restrict__ srcb, const int* __restrict__ dstb,
        const float* __restrict__ ew, const unsigned* __restrict__ offs,
        uint2* __restrict__ rec) {
    __shared__ unsigned cur[NBINS];
    for (int j = threadIdx.x; j < NBINS; j += NT)
        cur[j] = offs[(size_t)blockIdx.x * NBINS + j];
    __syncthreads();
    const int Q = NEDGES / 4;
    const int qpb = (Q + CB - 1) / CB;
    int q0 = blockIdx.x * qpb, q1 = min(q0 + qpb, Q);
    for (int i = q0 + threadIdx.x; i < q1; i += NT) {
        int4   s = loadIdx4NT<I64>(srcb, i);
        int4   d = loadIdx4NT<I64>(dstb, i);
        float4 w = loadF4NT(ew, i);
        int sv[4] = {clampIdx(s.x), clampIdx(s.y), clampIdx(s.z), clampIdx(s.w)};
        int dv[4] = {clampIdx(d.x), clampIdx(d.y), clampIdx(d.z), clampIdx(d.w)};
        float wv[4] = {w.x, w.y, w.z, w.w};
#pragma unroll
        for (int k = 0; k < 4; ++k) {
            int bin = dv[k] >> BINSHIFT;
            unsigned slot = atomicAdd(&cur[bin], 1u);
            unsigned key = ((unsigned)(dv[k] & BINMASK) << 19) | (unsigned)sv[k];
            rec[slot] = make_uint2(key, __float_as_uint(wv[k]));
        }
    }
}

__global__ __launch_bounds__(256) void kb_scatter(
        const int* __restrict__ ei, const int* __restrict__ flag,
        const float* __restrict__ ew, const unsigned* __restrict__ offs,
        uint2* __restrict__ rec) {
    if (flag[0]) scatter_body<true >(ei, ei + 2 * (size_t)NEDGES, ew, offs, rec);
    else         scatter_body<false>(ei, ei + (size_t)NEDGES,     ew, offs, rec);
}

// B4: per-bin degree accumulation in LDS (REP blocks/bin -> REP replicas).
__global__ __launch_bounds__(256) void kb_degree(
        const uint2* __restrict__ rec, const unsigned* __restrict__ base,
        float* __restrict__ degrep) {
    int bin = blockIdx.x >> 2, r = blockIdx.x & (REP - 1), t = threadIdx.x;
    __shared__ float sdeg[1 << BINSHIFT];
    for (int j = t; j < (1 << BINSHIFT); j += NT) sdeg[j] = 0.f;
    __syncthreads();
    int s = base[bin], e = base[bin + 1];
    int len = e - s;
    int b0 = s + (len * r) / REP;
    int b1 = s + (len * (r + 1)) / REP;
    for (int i = b0 + t; i < b1; i += NT) {
        uint2 rr = rec[i];
        atomAddF(&sdeg[rr.x >> 19], __uint_as_float(rr.y));
    }
    __syncthreads();
    int nodebase = bin << BINSHIFT;
    for (int j = t; j < (1 << BINSHIFT); j += NT) {
        int node = nodebase + j;
        if (node < NNODES) degrep[(size_t)r * NNODES + node] = sdeg[j];
    }
}

// dinv = rsqrt(sum of replicas + 1).
__global__ __launch_bounds__(256) void kb_dinv(
        const float* __restrict__ degrep, float* __restrict__ dinv, int N) {
    int i = blockIdx.x * blockDim.x + threadIdx.x;
    if (i >= N) return;
    float d = degrep[i] + degrep[(size_t)N + i]
            + degrep[2 * (size_t)N + i] + degrep[3 * (size_t)N + i];
    dinv[i] = rsqrtf(d + 1.0f);
}

// B5/B7: per-bin partial aggregation: out[dst] += dinv[src]*w*feat[src].
// (dinv[dst] factor applied later per-node in mid/fin.)
__global__ __launch_bounds__(256) void kb_agg(
        const uint2* __restrict__ rec, const unsigned* __restrict__ base,
        const float* __restrict__ dinv, const float2* __restrict__ feat,
        float2* __restrict__ outrep) {
    int bin = blockIdx.x >> 2, r = blockIdx.x & (REP - 1), t = threadIdx.x;
    __shared__ float sagg[2 << BINSHIFT];
    for (int j = t; j < (2 << BINSHIFT); j += NT) sagg[j] = 0.f;
    __syncthreads();
    int s = base[bin], e = base[bin + 1];
    int len = e - s;
    int b0 = s + (len * r) / REP;
    int b1 = s + (len * (r + 1)) / REP;
    for (int i = b0 + t; i < b1; i += NT) {
        uint2 rr = rec[i];
        int dl  = rr.x >> 19;
        int src = rr.x & 0x7FFFF;
        float nrm = dinv[src] * __uint_as_float(rr.y);
        float2 f = feat[src];
        atomAddF(&sagg[2 * dl],     f.x * nrm);
        atomAddF(&sagg[2 * dl + 1], f.y * nrm);
    }
    __syncthreads();
    int nodebase = bin << BINSHIFT;
    for (int j = t; j < (1 << BINSHIFT); j += NT) {
        int node = nodebase + j;
        if (node < NNODES)
            outrep[(size_t)r * NNODES + node] = make_float2(sagg[2 * j], sagg[2 * j + 1]);
    }
}

// layer-1 finish: v = dinv*(sum reps) + x*s^2; h2 = relu(v@W1+b1)@W2.
__global__ __launch_bounds__(256) void kb_mid(
        const float2* __restrict__ aggrep, const float2* __restrict__ x,
        const float* __restrict__ dinv, const float* __restrict__ W1,
        const float* __restrict__ b1, const float* __restrict__ W2,
        float2* __restrict__ h2, int N) {
    int i = blockIdx.x * blockDim.x + threadIdx.x;
    if (i >= N) return;
    float s = dinv[i], s2 = s * s;
    float2 a0 = aggrep[i],                 a1 = aggrep[(size_t)N + i];
    float2 a2 = aggrep[2 * (size_t)N + i], a3 = aggrep[3 * (size_t)N + i];
    float2 xa = x[i];
    float vx = s * (a0.x + a1.x + a2.x + a3.x) + xa.x * s2;
    float vy = s * (a0.y + a1.y + a2.y + a3.y) + xa.y * s2;
    float o0 = 0.f, o1 = 0.f;
#pragma unroll
    for (int j = 0; j < 8; ++j) {
        float tt = fmaf(vx, W1[j], fmaf(vy, W1[8 + j], b1[j]));
        tt = fmaxf(tt, 0.0f);
        o0 = fmaf(tt, W2[2 * j],     o0);
        o1 = fmaf(tt, W2[2 * j + 1], o1);
    }
    h2[i] = make_float2(o0, o1);
}

// layer-2 finish + softmax.
__global__ __launch_bounds__(256) void kb_fin(
        const float2* __restrict__ aggrep, const float2* __restrict__ h2,
        const float* __restrict__ dinv, const float* __restrict__ b2,
        float2* __restrict__ out, int N) {
    int i = blockIdx.x * blockDim.x + threadIdx.x;
    if (i >= N) return;
    float s = dinv[i], s2 = s * s;
    float2 a0 = aggrep[i],                 a1 = aggrep[(size_t)N + i];
    float2 a2 = aggrep[2 * (size_t)N + i], a3 = aggrep[3 * (size_t)N + i];
    float2 h = h2[i];
    float o0 = s * (a0.x + a1.x + a2.x + a3.x) + h.x * s2 + b2[0];
    float o1 = s * (a0.y + a1.y + a2.y + a3.y) + h.y * s2 + b2[1];
    float m  = fmaxf(o0, o1);
    float e0 = expf(o0 - m), e1 = expf(o1 - m);
    float inv = 1.0f / (e0 + e1);
    out[i] = make_float2(e0 * inv, e1 * inv);
}

// ---- FALLBACK PATH (round-7 proven kernels) --------------------------------

__global__ __launch_bounds__(256) void k_zero(float4* __restrict__ p, int n4) {
    int stride = gridDim.x * blockDim.x;
    for (int i = blockIdx.x * blockDim.x + threadIdx.x; i < n4; i += stride)
        p[i] = make_float4(0.f, 0.f, 0.f, 0.f);
}

template <bool I64>
__device__ __forceinline__ void degree_body(
        const int* __restrict__ dst, const float* __restrict__ ew,
        float* __restrict__ deg, int Q) {
    int stride = gridDim.x * blockDim.x;
    for (int i = blockIdx.x * blockDim.x + threadIdx.x; i < Q; i += stride) {
        int4   d = loadIdx4<I64>(dst, i);
        float4 w = ((const float4*)ew)[i];
        atomAddF(&deg[clampIdx(d.x)], w.x);
        atomAddF(&deg[clampIdx(d.y)], w.y);
        atomAddF(&deg[clampIdx(d.z)], w.z);
        atomAddF(&deg[clampIdx(d.w)], w.w);
    }
}

__global__ __launch_bounds__(256) void k_degree(
        const int* __restrict__ ei, const int* __restrict__ flag,
        const float* __restrict__ ew, float* __restrict__ deg, int Q) {
    if (flag[0]) degree_body<true >(ei + 2 * (size_t)NEDGES, ew, deg, Q);
    else         degree_body<false>(ei + (size_t)NEDGES,     ew, deg, Q);
}

__global__ __launch_bounds__(256) void k_dinv(float* __restrict__ deg, int N) {
    int i = blockIdx.x * blockDim.x + threadIdx.x;
    if (i >= N) return;
    deg[i] = rsqrtf(deg[i] + 1.0f);
}

template <bool I64>
__device__ __forceinline__ void edge_body(
        const int* __restrict__ src, const int* __restrict__ dst,
        const float* __restrict__ ew, const float* __restrict__ dinv,
        const float* __restrict__ feat, float* __restrict__ agg, int Q) {
    int stride = gridDim.x * blockDim.x;
    for (int i = blockIdx.x * blockDim.x + threadIdx.x; i < Q; i += stride) {
        int4   s = loadIdx4<I64>(src, i);
        int4   d = loadIdx4<I64>(dst, i);
        float4 w = ((const float4*)ew)[i];
        s.x = clampIdx(s.x); s.y = clampIdx(s.y);
        s.z = clampIdx(s.z); s.w = clampIdx(s.w);
        d.x = clampIdx(d.x); d.y = clampIdx(d.y);
        d.z = clampIdx(d.z); d.w = clampIdx(d.w);
        float n0 = dinv[s.x] * w.x * dinv[d.x];
        float n1 = dinv[s.y] * w.y * dinv[d.y];
        float n2 = dinv[s.z] * w.z * dinv[d.z];
        float n3 = dinv[s.w] * w.w * dinv[d.w];
        float2 f0 = ((const float2*)feat)[s.x];
        float2 f1 = ((const float2*)feat)[s.y];
        float2 f2 = ((const float2*)feat)[s.z];
        float2 f3 = ((const float2*)feat)[s.w];
        float* o0 = agg + 2 * (size_t)d.x;
        float* o1 = agg + 2 * (size_t)d.y;
        float* o2 = agg + 2 * (size_t)d.z;
        float* o3 = agg + 2 * (size_t)d.w;
        atomAddF(o0,     f0.x * n0);
        atomAddF(o0 + 1, f0.y * n0);
        atomAddF(o1,     f1.x * n1);
        atomAddF(o1 + 1, f1.y * n1);
        atomAddF(o2,     f2.x * n2);
        atomAddF(o2 + 1, f2.y * n2);
        atomAddF(o3,     f3.x * n3);
        atomAddF(o3 + 1, f3.y * n3);
    }
}

__global__ __launch_bounds__(256) void k_edge(
        const int* __restrict__ ei, const int* __restrict__ flag,
        const float* __restrict__ ew, const float* __restrict__ dinv,
        const float* __restrict__ feat, float* __restrict__ agg, int Q) {
    if (flag[0]) edge_body<true >(ei, ei + 2 * (size_t)NEDGES, ew, dinv, feat, agg, Q);
    else         edge_body<false>(ei, ei + (size_t)NEDGES,     ew, dinv, feat, agg, Q);
}

__global__ __launch_bounds__(256) void k_mid(
        const float* __restrict__ aggX, const float* __restrict__ x,
        const float* __restrict__ dinv, const float* __restrict__ W1,
        const float* __restrict__ b1, const float* __restrict__ W2,
        float* __restrict__ h2, int N) {
    int i = blockIdx.x * blockDim.x + threadIdx.x;
    if (i >= N) return;
    float s = dinv[i], s2 = s * s;
    float2 xa = ((const float2*)x)[i];
    float2 ag = ((const float2*)aggX)[i];
    float vx = ag.x + xa.x * s2;
    float vy = ag.y + xa.y * s2;
    float o0 = 0.f, o1 = 0.f;
#pragma unroll
    for (int j = 0; j < 8; ++j) {
        float t = fmaf(vx, W1[j], fmaf(vy, W1[8 + j], b1[j]));
        t = fmaxf(t, 0.0f);
        o0 = fmaf(t, W2[2 * j],     o0);
        o1 = fmaf(t, W2[2 * j + 1], o1);
    }
    ((float2*)h2)[i] = make_float2(o0, o1);
}

__global__ __launch_bounds__(256) void k_fin(
        const float* __restrict__ agg2, const float* __restrict__ h2,
        const float* __restrict__ dinv, const float* __restrict__ b2,
        float* __restrict__ out, int N) {
    int i = blockIdx.x * blockDim.x + threadIdx.x;
    if (i >= N) return;
    float s = dinv[i], s2 = s * s;
    float2 a = ((const float2*)agg2)[i];
    float2 h = ((const float2*)h2)[i];
    float o0 = a.x + h.x * s2 + b2[0];
    float o1 = a.y + h.y * s2 + b2[1];
    float m  = fmaxf(o0, o1);
    float e0 = expf(o0 - m), e1 = expf(o1 - m);
    float inv = 1.0f / (e0 + e1);
    ((float2*)out)[i] = make_float2(e0 * inv, e1 * inv);
}

// ---------------------------------------------------------------------------

extern "C" void kernel_launch(void* const* d_in, const int* in_sizes, int n_in,
                              void* d_out, int out_size, void* d_ws, size_t ws_size,
                              hipStream_t stream) {
    const float* x  = (const float*)d_in[0];
    const int*   ei = (const int*)d_in[1];   // int32 view; layout per flag
    const float* ew = (const float*)d_in[2];
    const float* W1 = (const float*)d_in[3];
    const float* b1 = (const float*)d_in[4];
    const float* W2 = (const float*)d_in[5];
    const float* b2 = (const float*)d_in[6];
    float* out = (float*)d_out;
    unsigned* wsu = (unsigned*)d_ws;
    float*    wsf = (float*)d_ws;

    const int N = NNODES, E = NEDGES, Q = E / 4;
    const int NB = (N + NT - 1) / NT;
    int* flag = (int*)(wsu + OFF_FLAG);

    bool fast = ws_size >= WS_NEED_FAST;

    k_detect<<<1, NT, 0, stream>>>(ei, flag);

    if (fast) {
        unsigned* base   = wsu + OFF_BASE;
        unsigned* tot    = wsu + OFF_TOT;
        unsigned* counts = wsu + OFF_COUNTS;
        unsigned* offs   = wsu + OFF_OFFS;
        float*    degrep = wsf + OFF_DEGREP;
        float*    dinv   = wsf + OFF_DINV;
        float2*   agg    = (float2*)(wsf + OFF_AGG);
        float2*   h2     = (float2*)(wsf + OFF_H2);
        uint2*    rec    = (uint2*)(wsu + OFF_REC);

        kb_count   <<<CB,          NT, 0, stream>>>(ei, flag, counts);
        kb_tot     <<<NBINS,       NT, 0, stream>>>(counts, tot);
        kb_scanbase<<<1,           NT, 0, stream>>>(tot, base);
        kb_offsets <<<NBINS,       NT, 0, stream>>>(counts, base, offs);
        kb_scatter <<<CB,          NT, 0, stream>>>(ei, flag, ew, offs, rec);
        kb_degree  <<<NBINS * REP, NT, 0, stream>>>(rec, base, degrep);
        kb_dinv    <<<NB,          NT, 0, stream>>>(degrep, dinv, N);
        kb_agg     <<<NBINS * REP, NT, 0, stream>>>(rec, base, dinv, (const float2*)x, agg);
        kb_mid     <<<NB,          NT, 0, stream>>>(agg, (const float2*)x, dinv, W1, b1, W2, h2, N);
        kb_agg     <<<NBINS * REP, NT, 0, stream>>>(rec, base, dinv, (const float2*)h2, agg);
        kb_fin     <<<NB,          NT, 0, stream>>>(agg, h2, dinv, b2, (float2*)out, N);
    } else {
        float* deg  = wsf + 64;
        float* aggX = wsf + 64 + (size_t)N;
        float* agg2 = wsf + 64 + (size_t)3 * N;
        float* h2   = wsf + 64 + (size_t)5 * N;
        const int EB = 2048;
        const int ZB = ((5 * N / 4) + NT - 1) / NT;

        k_zero  <<<ZB, NT, 0, stream>>>((float4*)deg, 5 * N / 4);
        k_degree<<<EB, NT, 0, stream>>>(ei, flag, ew, deg, Q);
        k_dinv  <<<NB, NT, 0, stream>>>(deg, N);
        k_edge  <<<EB, NT, 0, stream>>>(ei, flag, ew, deg, x, aggX, Q);
        k_mid   <<<NB, NT, 0, stream>>>(aggX, x, deg, W1, b1, W2, h2, N);
        k_edge  <<<EB, NT, 0, stream>>>(ei, flag, ew, deg, h2, agg2, Q);
        k_fin   <<<NB, NT, 0, stream>>>(agg2, h2, deg, b2, out, N);
    }
}

// Round 13
// 841.350 us; speedup vs baseline: 4.8654x; 1.0454x over previous
//
#include <hip/hip_runtime.h>
#include <math.h>

#define NNODES 500000
#define NEDGES 16000000
#define NBINS 256        // nodes/bin = 2048
#define BINSHIFT 11
#define BINMASK 2047
#define CB 1024          // blocks for count/scatter passes
#define REP 4            // blocks per bin for degree/agg
#define NT 256

// ---------------------------------------------------------------------------
// Round 13: round-12 + gather-diet for kb_agg (the 2x202us bottleneck,
// FETCH 674MB vs 128MB ideal = dinv+feat gather misses):
//  * premultiplied tables gx = dinv*x, g2 = dinv*z  -> ONE 8B gather/edge
//    from a 4MB table (fits one XCD L2) instead of two from 6MB
//  * nontemporal rec-stream loads in degree/agg so the 128MB stream does not
//    evict the gather table from L2
//
// ws layout (u32 words), total identical to round-12 (156,105,344 B):
//   0        flag
//   64       base[257]
//   1024     tot[256]
//   2048     counts[CB][NBINS]   (262144)   dead after scatter
//   264192   offs  [CB][NBINS]   (262144)   dead after scatter
//   526336   degrep[REP][N]      (2M words; dead after kb_dinv)
//   526336   g2[N][2]            (1M words; aliases degrep[0..2N], mid->fin)
//   1526336  gx[N][2]            (1M words; aliases degrep[2N..4N], gx->mid)
//   2526336  dinv[N]
//   3026336  agg[REP][N][2]      (4M words; agg1 then agg2, aliased)
//   7026336  rec[E] uint2        (key=(dstloc<<19)|src, w)
// ---------------------------------------------------------------------------

#define OFF_FLAG   0
#define OFF_BASE   64
#define OFF_TOT    1024
#define OFF_COUNTS 2048
#define OFF_OFFS   264192
#define OFF_DEGREP 526336
#define OFF_G2     526336
#define OFF_GX     1526336
#define OFF_DINV   2526336
#define OFF_AGG    3026336
#define OFF_REC    7026336
#define WS_NEED_FAST (((size_t)OFF_REC + 2ull * NEDGES) * 4ull)

// Native clang vector types for __builtin_nontemporal_load.
typedef int       i32x4 __attribute__((ext_vector_type(4)));
typedef float     f32x4 __attribute__((ext_vector_type(4)));
typedef long long i64x2 __attribute__((ext_vector_type(2)));
typedef unsigned  u32x2 __attribute__((ext_vector_type(2)));

__device__ __forceinline__ void atomAddF(float* p, float v) {
    unsafeAtomicAdd(p, v);  // native f32 add: global_atomic_add_f32 / ds_add_f32
}

__device__ __forceinline__ int clampIdx(int i) {
    return ((unsigned)i < (unsigned)NNODES) ? i : 0;
}

template <bool I64>
__device__ __forceinline__ int4 loadIdx4(const int* __restrict__ p, int i) {
    if (!I64) {
        return ((const int4*)p)[i];
    } else {
        const longlong2* q = (const longlong2*)p;
        longlong2 a = q[2 * i];
        longlong2 b = q[2 * i + 1];
        return make_int4((int)a.x, (int)a.y, (int)b.x, (int)b.y);
    }
}

// Nontemporal variants for the big streaming passes (clang vector types).
template <bool I64>
__device__ __forceinline__ int4 loadIdx4NT(const int* __restrict__ p, int i) {
    if (!I64) {
        i32x4 v = __builtin_nontemporal_load(((const i32x4*)p) + i);
        return make_int4(v.x, v.y, v.z, v.w);
    } else {
        i64x2 a = __builtin_nontemporal_load(((const i64x2*)p) + 2 * i);
        i64x2 b = __builtin_nontemporal_load(((const i64x2*)p) + 2 * i + 1);
        return make_int4((int)a.x, (int)a.y, (int)b.x, (int)b.y);
    }
}

__device__ __forceinline__ float4 loadF4NT(const float* __restrict__ p, int i) {
    f32x4 v = __builtin_nontemporal_load(((const f32x4*)p) + i);
    return make_float4(v.x, v.y, v.z, v.w);
}

__device__ __forceinline__ uint2 loadRecNT(const uint2* __restrict__ p, int i) {
    u32x2 v = __builtin_nontemporal_load(((const u32x2*)p) + i);
    return make_uint2(v.x, v.y);
}

// dtype probe: int64 buffer has all-zero high words (indices < 2^31).
__global__ __launch_bounds__(256) void k_detect(
        const int* __restrict__ ei, int* __restrict__ flag) {
    __shared__ int any_nz;
    if (threadIdx.x == 0) any_nz = 0;
    __syncthreads();
    int nz = 0;
    const int SAMPLES = 1024;
    const int step = NEDGES / SAMPLES;
    for (int t = threadIdx.x; t < SAMPLES; t += blockDim.x) {
        int k = t * step;
        nz |= (ei[2 * k + 1] != 0);
    }
    if (nz) atomicOr(&any_nz, 1);
    __syncthreads();
    if (threadIdx.x == 0) flag[0] = any_nz ? 0 : 1;
}

// ---- FAST PATH -------------------------------------------------------------

// B1: per-block LDS histogram of dst bins (NT streaming reads).
template <bool I64>
__device__ __forceinline__ void count_body(
        const int* __restrict__ dstb, unsigned* __restrict__ counts) {
    __shared__ unsigned hist[NBINS];
    for (int j = threadIdx.x; j < NBINS; j += NT) hist[j] = 0;
    __syncthreads();
    const int Q = NEDGES / 4;
    const int qpb = (Q + CB - 1) / CB;
    int q0 = blockIdx.x * qpb, q1 = min(q0 + qpb, Q);
    for (int i = q0 + threadIdx.x; i < q1; i += NT) {
        int4 d = loadIdx4NT<I64>(dstb, i);
        atomicAdd(&hist[clampIdx(d.x) >> BINSHIFT], 1u);
        atomicAdd(&hist[clampIdx(d.y) >> BINSHIFT], 1u);
        atomicAdd(&hist[clampIdx(d.z) >> BINSHIFT], 1u);
        atomicAdd(&hist[clampIdx(d.w) >> BINSHIFT], 1u);
    }
    __syncthreads();
    for (int j = threadIdx.x; j < NBINS; j += NT)
        counts[(size_t)blockIdx.x * NBINS + j] = hist[j];
}

__global__ __launch_bounds__(256) void kb_count(
        const int* __restrict__ ei, const int* __restrict__ flag,
        unsigned* __restrict__ counts) {
    if (flag[0]) count_body<true >(ei + 2 * (size_t)NEDGES, counts);
    else         count_body<false>(ei + (size_t)NEDGES,     counts);
}

// T1: per-bin totals (sum over CB blocks; 4 elements/thread).
__global__ __launch_bounds__(256) void kb_tot(
        const unsigned* __restrict__ counts, unsigned* __restrict__ tot) {
    int j = blockIdx.x, t = threadIdx.x;
    __shared__ unsigned r[NT];
    unsigned s = 0;
#pragma unroll
    for (int k = 0; k < CB / NT; ++k)
        s += counts[(size_t)(t * (CB / NT) + k) * NBINS + j];
    r[t] = s;
    __syncthreads();
    for (int d = NT / 2; d > 0; d >>= 1) {
        if (t < d) r[t] += r[t + d];
        __syncthreads();
    }
    if (t == 0) tot[j] = r[0];
}

// S1: exclusive scan of NBINS(=256) totals -> base[0..NBINS].
__global__ __launch_bounds__(256) void kb_scanbase(
        const unsigned* __restrict__ tot, unsigned* __restrict__ base) {
    __shared__ unsigned sc[NBINS];
    int t = threadIdx.x;
    unsigned o = tot[t];
    sc[t] = o;
    __syncthreads();
    for (int d = 1; d < NBINS; d <<= 1) {
        unsigned a = (t >= d) ? sc[t - d] : 0u;
        __syncthreads();
        sc[t] += a;
        __syncthreads();
    }
    base[t] = sc[t] - o;
    if (t == NBINS - 1) base[NBINS] = sc[NBINS - 1];
}

// S2: per-bin exclusive scan over blocks -> absolute record offsets.
__global__ __launch_bounds__(256) void kb_offsets(
        const unsigned* __restrict__ counts, const unsigned* __restrict__ base,
        unsigned* __restrict__ offs) {
    int j = blockIdx.x, t = threadIdx.x;
    const int K = CB / NT;  // 4
    __shared__ unsigned part[NT];
    unsigned loc[K];
    unsigned s = 0;
#pragma unroll
    for (int k = 0; k < K; ++k) {
        loc[k] = counts[(size_t)(t * K + k) * NBINS + j];
        s += loc[k];
    }
    part[t] = s;
    __syncthreads();
    for (int d = 1; d < NT; d <<= 1) {
        unsigned a = (t >= d) ? part[t - d] : 0u;
        __syncthreads();
        part[t] += a;
        __syncthreads();
    }
    unsigned run = base[j] + part[t] - s;
#pragma unroll
    for (int k = 0; k < K; ++k) {
        offs[(size_t)(t * K + k) * NBINS + j] = run;
        run += loc[k];
    }
}

// B3: scatter edge records into per-bin segments (LDS cursors, NT reads).
template <bool I64>
__device__ __forceinline__ void scatter_body(
        const int* __restrict__ srcb, const int* __restrict__ dstb,
        const float* __restrict__ ew, const unsigned* __restrict__ offs,
        uint2* __restrict__ rec) {
    __shared__ unsigned cur[NBINS];
    for (int j = threadIdx.x; j < NBINS; j += NT)
        cur[j] = offs[(size_t)blockIdx.x * NBINS + j];
    __syncthreads();
    const int Q = NEDGES / 4;
    const int qpb = (Q + CB - 1) / CB;
    int q0 = blockIdx.x * qpb, q1 = min(q0 + qpb, Q);
    for (int i = q0 + threadIdx.x; i < q1; i += NT) {
        int4   s = loadIdx4NT<I64>(srcb, i);
        int4   d = loadIdx4NT<I64>(dstb, i);
        float4 w = loadF4NT(ew, i);
        int sv[4] = {clampIdx(s.x), clampIdx(s.y), clampIdx(s.z), clampIdx(s.w)};
        int dv[4] = {clampIdx(d.x), clampIdx(d.y), clampIdx(d.z), clampIdx(d.w)};
        float wv[4] = {w.x, w.y, w.z, w.w};
#pragma unroll
        for (int k = 0; k < 4; ++k) {
            int bin = dv[k] >> BINSHIFT;
            unsigned slot = atomicAdd(&cur[bin], 1u);
            unsigned key = ((unsigned)(dv[k] & BINMASK) << 19) | (unsigned)sv[k];
            rec[slot] = make_uint2(key, __float_as_uint(wv[k]));
        }
    }
}

__global__ __launch_bounds__(256) void kb_scatter(
        const int* __restrict__ ei, const int* __restrict__ flag,
        const float* __restrict__ ew, const unsigned* __restrict__ offs,
        uint2* __restrict__ rec) {
    if (flag[0]) scatter_body<true >(ei, ei + 2 * (size_t)NEDGES, ew, offs, rec);
    else         scatter_body<false>(ei, ei + (size_t)NEDGES,     ew, offs, rec);
}

// B4: per-bin degree accumulation in LDS (REP blocks/bin -> REP replicas).
__global__ __launch_bounds__(256) void kb_degree(
        const uint2* __restrict__ rec, const unsigned* __restrict__ base,
        float* __restrict__ degrep) {
    int bin = blockIdx.x >> 2, r = blockIdx.x & (REP - 1), t = threadIdx.x;
    __shared__ float sdeg[1 << BINSHIFT];
    for (int j = t; j < (1 << BINSHIFT); j += NT) sdeg[j] = 0.f;
    __syncthreads();
    int s = base[bin], e = base[bin + 1];
    int len = e - s;
    int b0 = s + (len * r) / REP;
    int b1 = s + (len * (r + 1)) / REP;
    for (int i = b0 + t; i < b1; i += NT) {
        uint2 rr = loadRecNT(rec, i);
        atomAddF(&sdeg[rr.x >> 19], __uint_as_float(rr.y));
    }
    __syncthreads();
    int nodebase = bin << BINSHIFT;
    for (int j = t; j < (1 << BINSHIFT); j += NT) {
        int node = nodebase + j;
        if (node < NNODES) degrep[(size_t)r * NNODES + node] = sdeg[j];
    }
}

// dinv = rsqrt(sum of replicas + 1).
__global__ __launch_bounds__(256) void kb_dinv(
        const float* __restrict__ degrep, float* __restrict__ dinv, int N) {
    int i = blockIdx.x * blockDim.x + threadIdx.x;
    if (i >= N) return;
    float d = degrep[i] + degrep[(size_t)N + i]
            + degrep[2 * (size_t)N + i] + degrep[3 * (size_t)N + i];
    dinv[i] = rsqrtf(d + 1.0f);
}

// gx[i] = dinv[i] * x[i]  (separate kernel: gx aliases degrep[2N..4N], so it
// must run after kb_dinv has consumed all degree replicas).
__global__ __launch_bounds__(256) void kb_gx(
        const float* __restrict__ dinv, const float2* __restrict__ x,
        float2* __restrict__ gx, int N) {
    int i = blockIdx.x * blockDim.x + threadIdx.x;
    if (i >= N) return;
    float s = dinv[i];
    float2 xv = x[i];
    gx[i] = make_float2(s * xv.x, s * xv.y);
}

// B5/B7: per-bin partial aggregation: out[dst] += w * feat[src], where feat
// is the PREMULTIPLIED table (gx or g2). Single 8B gather per record.
__global__ __launch_bounds__(256) void kb_agg(
        const uint2* __restrict__ rec, const unsigned* __restrict__ base,
        const float2* __restrict__ feat, float2* __restrict__ outrep) {
    int bin = blockIdx.x >> 2, r = blockIdx.x & (REP - 1), t = threadIdx.x;
    __shared__ float sagg[2 << BINSHIFT];
    for (int j = t; j < (2 << BINSHIFT); j += NT) sagg[j] = 0.f;
    __syncthreads();
    int s = base[bin], e = base[bin + 1];
    int len = e - s;
    int b0 = s + (len * r) / REP;
    int b1 = s + (len * (r + 1)) / REP;
    for (int i = b0 + t; i < b1; i += NT) {
        uint2 rr = loadRecNT(rec, i);
        int dl  = rr.x >> 19;
        int src = rr.x & 0x7FFFF;
        float w = __uint_as_float(rr.y);
        float2 f = feat[src];
        atomAddF(&sagg[2 * dl],     f.x * w);
        atomAddF(&sagg[2 * dl + 1], f.y * w);
    }
    __syncthreads();
    int nodebase = bin << BINSHIFT;
    for (int j = t; j < (1 << BINSHIFT); j += NT) {
        int node = nodebase + j;
        if (node < NNODES)
            outrep[(size_t)r * NNODES + node] = make_float2(sagg[2 * j], sagg[2 * j + 1]);
    }
}

// layer-1 finish: v = s*(sum reps + gx); z = relu(v@W1+b1)@W2; g2 = s*z.
__global__ __launch_bounds__(256) void kb_mid(
        const float2* __restrict__ aggrep, const float2* __restrict__ gx,
        const float* __restrict__ dinv, const float* __restrict__ W1,
        const float* __restrict__ b1, const float* __restrict__ W2,
        float2* __restrict__ g2, int N) {
    int i = blockIdx.x * blockDim.x + threadIdx.x;
    if (i >= N) return;
    float s = dinv[i];
    float2 a0 = aggrep[i],                 a1 = aggrep[(size_t)N + i];
    float2 a2 = aggrep[2 * (size_t)N + i], a3 = aggrep[3 * (size_t)N + i];
    float2 g = gx[i];
    float vx = s * (a0.x + a1.x + a2.x + a3.x + g.x);
    float vy = s * (a0.y + a1.y + a2.y + a3.y + g.y);
    float o0 = 0.f, o1 = 0.f;
#pragma unroll
    for (int j = 0; j < 8; ++j) {
        float tt = fmaf(vx, W1[j], fmaf(vy, W1[8 + j], b1[j]));
        tt = fmaxf(tt, 0.0f);
        o0 = fmaf(tt, W2[2 * j],     o0);
        o1 = fmaf(tt, W2[2 * j + 1], o1);
    }
    g2[i] = make_float2(s * o0, s * o1);
}

// layer-2 finish + softmax: o = s*(sum reps + g2) + b2.
__global__ __launch_bounds__(256) void kb_fin(
        const float2* __restrict__ aggrep, const float2* __restrict__ g2,
        const float* __restrict__ dinv, const float* __restrict__ b2,
        float2* __restrict__ out, int N) {
    int i = blockIdx.x * blockDim.x + threadIdx.x;
    if (i >= N) return;
    float s = dinv[i];
    float2 a0 = aggrep[i],                 a1 = aggrep[(size_t)N + i];
    float2 a2 = aggrep[2 * (size_t)N + i], a3 = aggrep[3 * (size_t)N + i];
    float2 g = g2[i];
    float o0 = s * (a0.x + a1.x + a2.x + a3.x + g.x) + b2[0];
    float o1 = s * (a0.y + a1.y + a2.y + a3.y + g.y) + b2[1];
    float m  = fmaxf(o0, o1);
    float e0 = expf(o0 - m), e1 = expf(o1 - m);
    float inv = 1.0f / (e0 + e1);
    out[i] = make_float2(e0 * inv, e1 * inv);
}

// ---- FALLBACK PATH (round-7 proven kernels) --------------------------------

__global__ __launch_bounds__(256) void k_zero(float4* __restrict__ p, int n4) {
    int stride = gridDim.x * blockDim.x;
    for (int i = blockIdx.x * blockDim.x + threadIdx.x; i < n4; i += stride)
        p[i] = make_float4(0.f, 0.f, 0.f, 0.f);
}

template <bool I64>
__device__ __forceinline__ void degree_body(
        const int* __restrict__ dst, const float* __restrict__ ew,
        float* __restrict__ deg, int Q) {
    int stride = gridDim.x * blockDim.x;
    for (int i = blockIdx.x * blockDim.x + threadIdx.x; i < Q; i += stride) {
        int4   d = loadIdx4<I64>(dst, i);
        float4 w = ((const float4*)ew)[i];
        atomAddF(&deg[clampIdx(d.x)], w.x);
        atomAddF(&deg[clampIdx(d.y)], w.y);
        atomAddF(&deg[clampIdx(d.z)], w.z);
        atomAddF(&deg[clampIdx(d.w)], w.w);
    }
}

__global__ __launch_bounds__(256) void k_degree(
        const int* __restrict__ ei, const int* __restrict__ flag,
        const float* __restrict__ ew, float* __restrict__ deg, int Q) {
    if (flag[0]) degree_body<true >(ei + 2 * (size_t)NEDGES, ew, deg, Q);
    else         degree_body<false>(ei + (size_t)NEDGES,     ew, deg, Q);
}

__global__ __launch_bounds__(256) void k_dinv(float* __restrict__ deg, int N) {
    int i = blockIdx.x * blockDim.x + threadIdx.x;
    if (i >= N) return;
    deg[i] = rsqrtf(deg[i] + 1.0f);
}

template <bool I64>
__device__ __forceinline__ void edge_body(
        const int* __restrict__ src, const int* __restrict__ dst,
        const float* __restrict__ ew, const float* __restrict__ dinv,
        const float* __restrict__ feat, float* __restrict__ agg, int Q) {
    int stride = gridDim.x * blockDim.x;
    for (int i = blockIdx.x * blockDim.x + threadIdx.x; i < Q; i += stride) {
        int4   s = loadIdx4<I64>(src, i);
        int4   d = loadIdx4<I64>(dst, i);
        float4 w = ((const float4*)ew)[i];
        s.x = clampIdx(s.x); s.y = clampIdx(s.y);
        s.z = clampIdx(s.z); s.w = clampIdx(s.w);
        d.x = clampIdx(d.x); d.y = clampIdx(d.y);
        d.z = clampIdx(d.z); d.w = clampIdx(d.w);
        float n0 = dinv[s.x] * w.x * dinv[d.x];
        float n1 = dinv[s.y] * w.y * dinv[d.y];
        float n2 = dinv[s.z] * w.z * dinv[d.z];
        float n3 = dinv[s.w] * w.w * dinv[d.w];
        float2 f0 = ((const float2*)feat)[s.x];
        float2 f1 = ((const float2*)feat)[s.y];
        float2 f2 = ((const float2*)feat)[s.z];
        float2 f3 = ((const float2*)feat)[s.w];
        float* o0 = agg + 2 * (size_t)d.x;
        float* o1 = agg + 2 * (size_t)d.y;
        float* o2 = agg + 2 * (size_t)d.z;
        float* o3 = agg + 2 * (size_t)d.w;
        atomAddF(o0,     f0.x * n0);
        atomAddF(o0 + 1, f0.y * n0);
        atomAddF(o1,     f1.x * n1);
        atomAddF(o1 + 1, f1.y * n1);
        atomAddF(o2,     f2.x * n2);
        atomAddF(o2 + 1, f2.y * n2);
        atomAddF(o3,     f3.x * n3);
        atomAddF(o3 + 1, f3.y * n3);
    }
}

__global__ __launch_bounds__(256) void k_edge(
        const int* __restrict__ ei, const int* __restrict__ flag,
        const float* __restrict__ ew, const float* __restrict__ dinv,
        const float* __restrict__ feat, float* __restrict__ agg, int Q) {
    if (flag[0]) edge_body<true >(ei, ei + 2 * (size_t)NEDGES, ew, dinv, feat, agg, Q);
    else         edge_body<false>(ei, ei + (size_t)NEDGES,     ew, dinv, feat, agg, Q);
}

__global__ __launch_bounds__(256) void k_mid(
        const float* __restrict__ aggX, const float* __restrict__ x,
        const float* __restrict__ dinv, const float* __restrict__ W1,
        const float* __restrict__ b1, const float* __restrict__ W2,
        float* __restrict__ h2, int N) {
    int i = blockIdx.x * blockDim.x + threadIdx.x;
    if (i >= N) return;
    float s = dinv[i], s2 = s * s;
    float2 xa = ((const float2*)x)[i];
    float2 ag = ((const float2*)aggX)[i];
    float vx = ag.x + xa.x * s2;
    float vy = ag.y + xa.y * s2;
    float o0 = 0.f, o1 = 0.f;
#pragma unroll
    for (int j = 0; j < 8; ++j) {
        float t = fmaf(vx, W1[j], fmaf(vy, W1[8 + j], b1[j]));
        t = fmaxf(t, 0.0f);
        o0 = fmaf(t, W2[2 * j],     o0);
        o1 = fmaf(t, W2[2 * j + 1], o1);
    }
    ((float2*)h2)[i] = make_float2(o0, o1);
}

__global__ __launch_bounds__(256) void k_fin(
        const float* __restrict__ agg2, const float* __restrict__ h2,
        const float* __restrict__ dinv, const float* __restrict__ b2,
        float* __restrict__ out, int N) {
    int i = blockIdx.x * blockDim.x + threadIdx.x;
    if (i >= N) return;
    float s = dinv[i], s2 = s * s;
    float2 a = ((const float2*)agg2)[i];
    float2 h = ((const float2*)h2)[i];
    float o0 = a.x + h.x * s2 + b2[0];
    float o1 = a.y + h.y * s2 + b2[1];
    float m  = fmaxf(o0, o1);
    float e0 = expf(o0 - m), e1 = expf(o1 - m);
    float inv = 1.0f / (e0 + e1);
    ((float2*)out)[i] = make_float2(e0 * inv, e1 * inv);
}

// ---------------------------------------------------------------------------

extern "C" void kernel_launch(void* const* d_in, const int* in_sizes, int n_in,
                              void* d_out, int out_size, void* d_ws, size_t ws_size,
                              hipStream_t stream) {
    const float* x  = (const float*)d_in[0];
    const int*   ei = (const int*)d_in[1];   // int32 view; layout per flag
    const float* ew = (const float*)d_in[2];
    const float* W1 = (const float*)d_in[3];
    const float* b1 = (const float*)d_in[4];
    const float* W2 = (const float*)d_in[5];
    const float* b2 = (const float*)d_in[6];
    float* out = (float*)d_out;
    unsigned* wsu = (unsigned*)d_ws;
    float*    wsf = (float*)d_ws;

    const int N = NNODES, E = NEDGES, Q = E / 4;
    const int NB = (N + NT - 1) / NT;
    int* flag = (int*)(wsu + OFF_FLAG);

    bool fast = ws_size >= WS_NEED_FAST;

    k_detect<<<1, NT, 0, stream>>>(ei, flag);

    if (fast) {
        unsigned* base   = wsu + OFF_BASE;
        unsigned* tot    = wsu + OFF_TOT;
        unsigned* counts = wsu + OFF_COUNTS;
        unsigned* offs   = wsu + OFF_OFFS;
        float*    degrep = wsf + OFF_DEGREP;
        float*    dinv   = wsf + OFF_DINV;
        float2*   gx     = (float2*)(wsf + OFF_GX);
        float2*   g2     = (float2*)(wsf + OFF_G2);
        float2*   agg    = (float2*)(wsf + OFF_AGG);
        uint2*    rec    = (uint2*)(wsu + OFF_REC);

        kb_count   <<<CB,          NT, 0, stream>>>(ei, flag, counts);
        kb_tot     <<<NBINS,       NT, 0, stream>>>(counts, tot);
        kb_scanbase<<<1,           NT, 0, stream>>>(tot, base);
        kb_offsets <<<NBINS,       NT, 0, stream>>>(counts, base, offs);
        kb_scatter <<<CB,          NT, 0, stream>>>(ei, flag, ew, offs, rec);
        kb_degree  <<<NBINS * REP, NT, 0, stream>>>(rec, base, degrep);
        kb_dinv    <<<NB,          NT, 0, stream>>>(degrep, dinv, N);
        kb_gx      <<<NB,          NT, 0, stream>>>(dinv, (const float2*)x, gx, N);
        kb_agg     <<<NBINS * REP, NT, 0, stream>>>(rec, base, gx, agg);
        kb_mid     <<<NB,          NT, 0, stream>>>(agg, gx, dinv, W1, b1, W2, g2, N);
        kb_agg     <<<NBINS * REP, NT, 0, stream>>>(rec, base, g2, agg);
        kb_fin     <<<NB,          NT, 0, stream>>>(agg, g2, dinv, b2, (float2*)out, N);
    } else {
        float* deg  = wsf + 64;
        float* aggX = wsf + 64 + (size_t)N;
        float* agg2 = wsf + 64 + (size_t)3 * N;
        float* h2   = wsf + 64 + (size_t)5 * N;
        const int EB = 2048;
        const int ZB = ((5 * N / 4) + NT - 1) / NT;

        k_zero  <<<ZB, NT, 0, stream>>>((float4*)deg, 5 * N / 4);
        k_degree<<<EB, NT, 0, stream>>>(ei, flag, ew, deg, Q);
        k_dinv  <<<NB, NT, 0, stream>>>(deg, N);
        k_edge  <<<EB, NT, 0, stream>>>(ei, flag, ew, deg, x, aggX, Q);
        k_mid   <<<NB, NT, 0, stream>>>(aggX, x, deg, W1, b1, W2, h2, N);
        k_edge  <<<EB, NT, 0, stream>>>(ei, flag, ew, deg, h2, agg2, Q);
        k_fin   <<<NB, NT, 0, stream>>>(agg2, h2, deg, b2, out, N);
    }
}